// Round 19
// baseline (471.223 us; speedup 1.0000x reference)
//
#include <hip/hip_runtime.h>
#include <hip/hip_bf16.h>

// Problem constants
constexpr int LQ  = 1024;  // L1 == L2 == 1024
constexpr int BN  = 8;
constexpr int D1N = 512;
constexpr int D2N = 1024;
constexpr int HN  = 16;
constexpr int MN  = 1024;
constexpr int DPH = 64;

typedef __attribute__((ext_vector_type(8)))  short bf16x8;   // 8 bf16 in 4 VGPRs
typedef __attribute__((ext_vector_type(2)))  float f32x2;
typedef __attribute__((ext_vector_type(4)))  float f32x4;
typedef __attribute__((ext_vector_type(16))) float f32x16;

__device__ __forceinline__ unsigned short f2bf(float f) {
  unsigned u = __float_as_uint(f);
  u += 0x7FFFu + ((u >> 16) & 1u);   // RNE
  return (unsigned short)(u >> 16);
}
__device__ __forceinline__ float bf2f(unsigned short u) {
  return __uint_as_float(((unsigned)u) << 16);
}
__device__ __forceinline__ float rcpf(float x) {
  float r;
  asm("v_rcp_f32 %0, %1" : "=v"(r) : "v"(x));
  return r;
}

__device__ __forceinline__ f32x4 mfma16(bf16x8 a, bf16x8 b, f32x4 c) {
  return __builtin_amdgcn_mfma_f32_16x16x32_bf16(a, b, c, 0, 0, 0);
}
__device__ __forceinline__ f32x16 mfma32(bf16x8 a, bf16x8 b, f32x16 c) {
  return __builtin_amdgcn_mfma_f32_32x32x16_bf16(a, b, c, 0, 0, 0);
}
__device__ __forceinline__ f32x16 zero16() {
  f32x16 z;
#pragma unroll
  for (int i = 0; i < 16; ++i) z[i] = 0.f;
  return z;
}

__device__ __forceinline__ unsigned cvtpk(float lo, float hi) {
  unsigned r;
  asm("v_cvt_pk_bf16_f32 %0, %1, %2" : "=v"(r) : "v"(lo), "v"(hi));
  return r;
}

// LDS-visibility barrier WITHOUT the vmcnt(0) drain __syncthreads() emits.
// (Correctness-proven R7-R18.)
__device__ __forceinline__ void lds_barrier() {
  asm volatile("s_waitcnt lgkmcnt(0)" ::: "memory");
  __builtin_amdgcn_s_barrier();
}

// async global->LDS, 16B per lane. LDS dest = wave-uniform base + lane*16
// (HW semantics, guide m97/m104); global src is per-lane. Increments vmcnt.
__device__ __forceinline__ void gload_lds16(const unsigned short* g, unsigned short* l) {
  __builtin_amdgcn_global_load_lds(
      (const __attribute__((address_space(1))) unsigned int*)g,
      (__attribute__((address_space(3))) unsigned int*)l,
      16, 0, 0);
}

// Build PV A-fragment from 8 P values (C-layout row=(reg&3)+8*(reg>>2)+4*(lane>>5)).
__device__ __forceinline__ bf16x8 pfrag(const float* p) {
  unsigned x0 = cvtpk(p[0], p[1]), y0 = cvtpk(p[4], p[5]);
  unsigned x1 = cvtpk(p[2], p[3]), y1 = cvtpk(p[6], p[7]);
  asm volatile("v_permlane32_swap_b32 %0, %1" : "+v"(x0), "+v"(y0));
  asm volatile("v_permlane32_swap_b32 %0, %1" : "+v"(x1), "+v"(y1));
  union { unsigned u[4]; bf16x8 v; } r;
  r.u[0] = x0; r.u[1] = x1; r.u[2] = y0; r.u[3] = y1;
  return r.v;
}

__device__ __forceinline__ bf16x8 pack8(f32x4 p0, f32x4 p1) {
  bf16x8 o;
  o[0] = (short)f2bf(p0[0]); o[1] = (short)f2bf(p0[1]);
  o[2] = (short)f2bf(p0[2]); o[3] = (short)f2bf(p0[3]);
  o[4] = (short)f2bf(p1[0]); o[5] = (short)f2bf(p1[1]);
  o[6] = (short)f2bf(p1[2]); o[7] = (short)f2bf(p1[3]);
  return o;
}
// Fast frag-convert via v_cvt_pk_bf16_f32 (RNE)
__device__ __forceinline__ bf16x8 pack8q(f32x4 lo, f32x4 hi) {
  union { unsigned u[4]; bf16x8 v; } r;
  r.u[0] = cvtpk(lo[0], lo[1]); r.u[1] = cvtpk(lo[2], lo[3]);
  r.u[2] = cvtpk(hi[0], hi[1]); r.u[3] = cvtpk(hi[2], hi[3]);
  return r.v;
}

// ---------------------------------------------------------------- merged cvt
// All six weight f32->bf16 conversions in ONE dispatch (R18).
struct CvtArgs {
  const float* src[6];
  unsigned short* dst[6];
  int cum[7];   // cumulative x8-element counts
};
__global__ __launch_bounds__(256) void cvt6_kernel(CvtArgs a) {
  int i = blockIdx.x * blockDim.x + threadIdx.x;
  if (i >= a.cum[6]) return;
  int s = 0;
#pragma unroll
  for (int j = 1; j < 6; ++j) s += (i >= a.cum[j]) ? 1 : 0;
  int off = i - a.cum[s];
  const f32x4* sp = (const f32x4*)a.src[s];
  f32x4 x = sp[2 * off], y = sp[2 * off + 1];
  ((bf16x8*)a.dst[s])[off] = pack8(x, y);
}

// ---------------------------------------------------------------- staged GEMM
// A [rows,K] row-major (f32 if AF32, else bf16); W [1024,K] bf16 row-major.
// C = A @ W^T + bias. 128x128 tile, BK=32, reg-staged LDS, 2-phase with
// lgkmcnt-only barriers (R8-validated). AF32: cvt folded into LDS write.
// MODE 0: bf16 to [B,H,L,64]; MODE 2: f32 row-major [rows,1024]
template <int K, int MODE, bool AF32>
__device__ __forceinline__ void gemm_body(const void* __restrict__ Ap,
                                          const unsigned short* __restrict__ W,
                                          const float* __restrict__ bias,
                                          void* __restrict__ outp,
                                          int rowb, int colb) {
  __shared__ unsigned short As[128 * 40], Bs[128 * 40];
  const int tid = threadIdx.x, wave = tid >> 6, lane = tid & 63;
  const int lg = lane >> 4, lm = lane & 15;
  const int wrow = (wave >> 1) * 64, wcol = (wave & 1) * 64;
  const int sr = tid >> 1, sh = (tid & 1) * 16;
  const unsigned short* Arow = AF32 ? nullptr
      : (const unsigned short*)Ap + (size_t)(rowb + sr) * K + sh;
  const float* ArowF = AF32 ? (const float*)Ap + (size_t)(rowb + sr) * K + sh
                            : nullptr;
  const unsigned short* Wrow = W + (size_t)(colb + sr) * K + sh;

  f32x4 acc[4][4];
#pragma unroll
  for (int i = 0; i < 4; ++i)
#pragma unroll
    for (int j = 0; j < 4; ++j) acc[i][j] = (f32x4){0.f, 0.f, 0.f, 0.f};

  f32x4 fa0, fa1, fa2, fa3;
  bf16x8 a0, a1, b0, b1;
  if (AF32) {
    fa0 = *(const f32x4*)(ArowF);     fa1 = *(const f32x4*)(ArowF + 4);
    fa2 = *(const f32x4*)(ArowF + 8); fa3 = *(const f32x4*)(ArowF + 12);
  } else {
    a0 = *(const bf16x8*)(Arow);
    a1 = *(const bf16x8*)(Arow + 8);
  }
  b0 = *(const bf16x8*)(Wrow);
  b1 = *(const bf16x8*)(Wrow + 8);

  for (int kk = 0; kk < K; kk += 32) {
    lds_barrier();   // previous iteration's LDS frag reads complete
    if (AF32) {
      *(bf16x8*)&As[sr * 40 + sh]     = pack8q(fa0, fa1);
      *(bf16x8*)&As[sr * 40 + sh + 8] = pack8q(fa2, fa3);
    } else {
      *(bf16x8*)&As[sr * 40 + sh] = a0;
      *(bf16x8*)&As[sr * 40 + sh + 8] = a1;
    }
    *(bf16x8*)&Bs[sr * 40 + sh] = b0;
    *(bf16x8*)&Bs[sr * 40 + sh + 8] = b1;
    const int kn = (kk + 32 < K) ? kk + 32 : 0;   // clamped harmless reload
    if (AF32) {
      fa0 = *(const f32x4*)(ArowF + kn);     fa1 = *(const f32x4*)(ArowF + kn + 4);
      fa2 = *(const f32x4*)(ArowF + kn + 8); fa3 = *(const f32x4*)(ArowF + kn + 12);
    } else {
      a0 = *(const bf16x8*)(Arow + kn);
      a1 = *(const bf16x8*)(Arow + kn + 8);
    }
    b0 = *(const bf16x8*)(Wrow + kn);
    b1 = *(const bf16x8*)(Wrow + kn + 8);
    lds_barrier();   // staged writes visible
    bf16x8 af[4], wf[4];
#pragma unroll
    for (int i = 0; i < 4; ++i) af[i] = *(const bf16x8*)&As[(wrow + i * 16 + lm) * 40 + lg * 8];
#pragma unroll
    for (int j = 0; j < 4; ++j) wf[j] = *(const bf16x8*)&Bs[(wcol + j * 16 + lm) * 40 + lg * 8];
#pragma unroll
    for (int i = 0; i < 4; ++i)
#pragma unroll
      for (int j = 0; j < 4; ++j) acc[i][j] = mfma16(af[i], wf[j], acc[i][j]);
  }

#pragma unroll
  for (int j = 0; j < 4; ++j) {
    int col = colb + wcol + j * 16 + lm;
    float bs = bias[col];
#pragma unroll
    for (int i = 0; i < 4; ++i) {
#pragma unroll
      for (int r = 0; r < 4; ++r) {
        int row = rowb + wrow + i * 16 + lg * 4 + r;
        float v = acc[i][j][r] + bs;
        if (MODE == 0) {
          int l = row >> 3, bb = row & 7, h = col >> 6, d = col & 63;
          ((unsigned short*)outp)[(((size_t)(bb * HN + h)) * LQ + l) * DPH + d] = f2bf(v);
        } else {
          ((float*)outp)[(size_t)row * MN + col] = v;
        }
      }
    }
  }
}

// Paired projections (f32 A, cvt folded). sel in blockIdx.y-MSB so the K/V
// pair sharing an A-panel has the SAME blockIdx.x -> same XCD (R14).
template <int K>
__global__ __launch_bounds__(256) void gemm_pair_f32_kernel(
    const float* __restrict__ A,
    const unsigned short* __restrict__ W0, const unsigned short* __restrict__ W1,
    const float* __restrict__ b0, const float* __restrict__ b1,
    void* __restrict__ o0, void* __restrict__ o1) {
  const int sel = blockIdx.y >> 3;
  gemm_body<K, 0, true>(A, sel ? W1 : W0, sel ? b1 : b0, sel ? o1 : o0,
                        blockIdx.x * 128, (blockIdx.y & 7) * 128);
}

// ---------------------------------------------------------------- final GEMM
// Dual final projections, global_load_lds staged (R19; guide m97/m151:
// gload_lds width-16 beats reg-staging at 128^2 tiles, 874 vs 646 TF).
// Both operands bf16. Linear [128][32] LDS tiles (NO padding: gload_lds
// needs contiguous dest), double-buffered; per iter: stage(next) -> frag
// reads + 16 MFMA on cur -> vmcnt(0)+lgkmcnt(0)+barrier (staging loads fly
// under the whole MFMA block).
// Staging map: wave w, round j, lane l covers tile byte t=(w*2+j)*1024+l*16
// -> row=t>>6, col elem=(t&63)>>1; LDS base uniform (HW adds lane*16).
template <int K>
__global__ __launch_bounds__(256) void gemm_lds_dual_kernel(
    const unsigned short* __restrict__ A0, const unsigned short* __restrict__ A1,
    const unsigned short* __restrict__ W0, const unsigned short* __restrict__ W1,
    const float* __restrict__ b0, const float* __restrict__ b1,
    float* __restrict__ o0, float* __restrict__ o1) {
  const int sel = blockIdx.y >> 3;
  const unsigned short* A = sel ? A1 : A0;
  const unsigned short* W = sel ? W1 : W0;
  const float* bias = sel ? b1 : b0;
  float* outp = sel ? o1 : o0;
  const int rowb = blockIdx.x * 128, colb = (blockIdx.y & 7) * 128;

  __shared__ unsigned short As[2][128 * 32], Bs[2][128 * 32];   // 32 KB
  const int tid = threadIdx.x, wave = tid >> 6, lane = tid & 63;
  const int lg = lane >> 4, lm = lane & 15;
  const int wrow = (wave >> 1) * 64, wcol = (wave & 1) * 64;

  // per-(wave,round) staging geometry
  const int t0 = (wave * 2 + 0) * 1024 + lane * 16;   // byte in 8KB tile
  const int t1 = (wave * 2 + 1) * 1024 + lane * 16;
  const int r0 = t0 >> 6, c0 = (t0 & 63) >> 1;
  const int r1 = t1 >> 6, c1 = (t1 & 63) >> 1;
  const int lb0 = (wave * 2 + 0) * 512;   // uniform LDS short-offset base
  const int lb1 = (wave * 2 + 1) * 512;

  f32x4 acc[4][4];
#pragma unroll
  for (int i = 0; i < 4; ++i)
#pragma unroll
    for (int j = 0; j < 4; ++j) acc[i][j] = (f32x4){0.f, 0.f, 0.f, 0.f};

  auto stage = [&](int buf, int kk) {
    gload_lds16(A + (size_t)(rowb + r0) * K + kk + c0, &As[buf][lb0]);
    gload_lds16(A + (size_t)(rowb + r1) * K + kk + c1, &As[buf][lb1]);
    gload_lds16(W + (size_t)(colb + r0) * K + kk + c0, &Bs[buf][lb0]);
    gload_lds16(W + (size_t)(colb + r1) * K + kk + c1, &Bs[buf][lb1]);
  };

  // prologue
  stage(0, 0);
  asm volatile("s_waitcnt vmcnt(0)" ::: "memory");
  __builtin_amdgcn_s_barrier();

  int cur = 0;
  for (int kk = 0; kk < K; kk += 32) {
    if (kk + 32 < K) stage(cur ^ 1, kk + 32);   // in flight under MFMA below
    bf16x8 af[4], wf[4];
#pragma unroll
    for (int i = 0; i < 4; ++i) af[i] = *(const bf16x8*)&As[cur][(wrow + i * 16 + lm) * 32 + lg * 8];
#pragma unroll
    for (int j = 0; j < 4; ++j) wf[j] = *(const bf16x8*)&Bs[cur][(wcol + j * 16 + lm) * 32 + lg * 8];
#pragma unroll
    for (int i = 0; i < 4; ++i)
#pragma unroll
      for (int j = 0; j < 4; ++j) acc[i][j] = mfma16(af[i], wf[j], acc[i][j]);
    asm volatile("s_waitcnt vmcnt(0) lgkmcnt(0)" ::: "memory");
    __builtin_amdgcn_s_barrier();
    cur ^= 1;
  }

#pragma unroll
  for (int j = 0; j < 4; ++j) {
    int col = colb + wcol + j * 16 + lm;
    float bs = bias[col];
#pragma unroll
    for (int i = 0; i < 4; ++i) {
#pragma unroll
      for (int r = 0; r < 4; ++r) {
        int row = rowb + wrow + i * 16 + lg * 4 + r;
        outp[(size_t)row * MN + col] = acc[i][j][r] + bs;
      }
    }
  }
}

// ---------------------------------------------------------------- V transpose
// BOTH V transposes in one dispatch (grid.z: 0 = V1 scaled, 1 = V2 plain).
__global__ __launch_bounds__(256) void transpose2_kernel(
    const unsigned short* __restrict__ V1, unsigned short* __restrict__ VT1,
    const float* __restrict__ scale1,
    const unsigned short* __restrict__ V2, unsigned short* __restrict__ VT2) {
  __shared__ unsigned short t[64][72];
  const int which = blockIdx.z;
  const unsigned short* V = which ? V2 : V1;
  unsigned short* VT = which ? VT2 : VT1;
  const float* scale = which ? nullptr : scale1;
  int bh = blockIdx.y, l0 = blockIdx.x * 64;
  int tid = threadIdx.x;
  int r = tid >> 2, c0 = (tid & 3) * 16;
  const unsigned short* src = V + ((size_t)bh * LQ + l0 + r) * DPH + c0;
  bf16x8 v0 = *(const bf16x8*)(src);
  bf16x8 v1 = *(const bf16x8*)(src + 8);
  if (scale) {
    float sc = scale[(size_t)bh * LQ + l0 + r];
#pragma unroll
    for (int j = 0; j < 8; ++j) {
      v0[j] = (short)f2bf(bf2f((unsigned short)v0[j]) * sc);
      v1[j] = (short)f2bf(bf2f((unsigned short)v1[j]) * sc);
    }
  }
  *(bf16x8*)&t[r][c0] = v0;
  *(bf16x8*)&t[r][c0 + 8] = v1;
  __syncthreads();
  int d = tid >> 2, lc = (tid & 3) * 16;
  bf16x8 o0, o1;
#pragma unroll
  for (int j = 0; j < 8; ++j) {
    o0[j] = (short)t[lc + j][d];
    o1[j] = (short)t[lc + 8 + j][d];
  }
  unsigned short* dst = VT + ((size_t)bh * DPH + d) * LQ + l0 + lc;
  *(bf16x8*)dst = o0;
  *(bf16x8*)(dst + 8) = o1;
}

// ---------------------------------------------------------------- col reduce
// inv_colsum[bh,k] = 1/sum_q exp(s[q,k]).  bh-major grid; reg prefetch (R18).
__global__ __launch_bounds__(256) void col_reduce_kernel(const unsigned short* __restrict__ K1p,
                                                         const unsigned short* __restrict__ K2p,
                                                         float* __restrict__ inv_colsum) {
  int bh = blockIdx.x, kb = blockIdx.y * 128;
  int wave = threadIdx.x >> 6, lane = threadIdx.x & 63, l31 = lane & 31, sg = lane >> 5;
  int k0w = kb + wave * 32;
  const unsigned short* k1 = K1p + (size_t)bh * LQ * DPH;
  const unsigned short* k2 = K2p + (size_t)bh * LQ * DPH;
  bf16x8 bk[4];
#pragma unroll
  for (int i = 0; i < 4; ++i)
    bk[i] = *(const bf16x8*)(k1 + (size_t)(k0w + l31) * DPH + i * 16 + sg * 8);
  bf16x8 aq[4];
#pragma unroll
  for (int i = 0; i < 4; ++i)
    aq[i] = *(const bf16x8*)(k2 + (size_t)(l31) * DPH + i * 16 + sg * 8);
  float tot = 0.f;
  for (int q0 = 0; q0 < LQ; q0 += 32) {
    const int qn = (q0 + 32) & (LQ - 1);   // harmless wrap reload on last
    bf16x8 aqn[4];
#pragma unroll
    for (int i = 0; i < 4; ++i)
      aqn[i] = *(const bf16x8*)(k2 + (size_t)(qn + l31) * DPH + i * 16 + sg * 8);
    f32x16 cs = zero16();
#pragma unroll
    for (int i = 0; i < 4; ++i) cs = mfma32(aq[i], bk[i], cs);
#pragma unroll
    for (int r = 0; r < 16; ++r) tot += __expf(cs[r]);
#pragma unroll
    for (int i = 0; i < 4; ++i) aq[i] = aqn[i];
  }
  tot += __shfl_xor(tot, 32);
  if (lane < 32) inv_colsum[(size_t)bh * LQ + k0w + lane] = 1.0f / tot;
}

// ---------------------------------------------------------------- ctx 1->2
// out[q][d] = sum_k exp(s[q,k]) * V1s[k][d]   (V1s pre-scaled by 1/colsum)
// bh-major grid; reg prefetch of next k-tile K1 frags (R18).
__global__ __launch_bounds__(256) void ctx12_kernel(const unsigned short* __restrict__ K1p,
                                                    const unsigned short* __restrict__ K2p,
                                                    const unsigned short* __restrict__ V1Ts,
                                                    unsigned short* __restrict__ c12) {
  int bh = blockIdx.x, b = bh >> 4, h = bh & 15;
  int wave = threadIdx.x >> 6, lane = threadIdx.x & 63, l31 = lane & 31, sg = lane >> 5;
  int q0 = blockIdx.y * 128 + wave * 32;
  const unsigned short* k1 = K1p + (size_t)bh * LQ * DPH;
  const unsigned short* k2 = K2p + (size_t)bh * LQ * DPH;
  const unsigned short* vt = V1Ts + (size_t)bh * DPH * LQ;

  bf16x8 bq[4];  // K2 rows q (B operand of score), hoisted
#pragma unroll
  for (int i = 0; i < 4; ++i)
    bq[i] = *(const bf16x8*)(k2 + (size_t)(q0 + l31) * DPH + i * 16 + sg * 8);

  bf16x8 ak[4];
#pragma unroll
  for (int i = 0; i < 4; ++i)
    ak[i] = *(const bf16x8*)(k1 + (size_t)(l31) * DPH + i * 16 + sg * 8);

  f32x16 acc0 = zero16(), acc1 = zero16();
  for (int k0 = 0; k0 < LQ; k0 += 32) {
    const int kn = (k0 + 32) & (LQ - 1);   // harmless wrap reload on last
    bf16x8 akn[4];
#pragma unroll
    for (int i = 0; i < 4; ++i)
      akn[i] = *(const bf16x8*)(k1 + (size_t)(kn + l31) * DPH + i * 16 + sg * 8);
    f32x16 cs = zero16();
#pragma unroll
    for (int i = 0; i < 4; ++i) cs = mfma32(ak[i], bq[i], cs);  // C[k][q]
    float p[16];
#pragma unroll
    for (int r = 0; r < 16; ++r) p[r] = __expf(cs[r]);
    bf16x8 pa0 = pfrag(p), pa1 = pfrag(p + 8);
    bf16x8 v00 = *(const bf16x8*)(vt + (size_t)l31 * LQ + k0 + sg * 8);
    bf16x8 v01 = *(const bf16x8*)(vt + (size_t)l31 * LQ + k0 + 16 + sg * 8);
    bf16x8 v10 = *(const bf16x8*)(vt + (size_t)(32 + l31) * LQ + k0 + sg * 8);
    bf16x8 v11 = *(const bf16x8*)(vt + (size_t)(32 + l31) * LQ + k0 + 16 + sg * 8);
    acc0 = mfma32(pa0, v00, acc0);
    acc0 = mfma32(pa1, v01, acc0);
    acc1 = mfma32(pa0, v10, acc1);
    acc1 = mfma32(pa1, v11, acc1);
#pragma unroll
    for (int i = 0; i < 4; ++i) ak[i] = akn[i];
  }
#pragma unroll
  for (int r = 0; r < 16; ++r) {
    int q = q0 + (r & 3) + 8 * (r >> 2) + 4 * sg;
    size_t base = ((size_t)q * BN + b) * MN + h * 64;
    c12[base + l31] = f2bf(acc0[r]);
    c12[base + 32 + l31] = f2bf(acc1[r]);
  }
}

// ---------------------------------------------------------------- ctx 2->1 FUSED
// v4 (R8/R14, best measured 131us): raw lds_barrier (no vmcnt drain -> V
// loads span 2 barriers, K2 loads prefetched one step ahead). Verified.
__global__ __launch_bounds__(1024) void ctx21_fused_kernel(const unsigned short* __restrict__ K1p,
                                                           const unsigned short* __restrict__ K2p,
                                                           const unsigned short* __restrict__ V2T,
                                                           unsigned short* __restrict__ c21) {
  constexpr int SP = 34;              // floats per k-row (pad)
  constexpr int WS = 32 * SP;         // 1088 floats per wave strip
  __shared__ float strip[16 * WS];    // 69632 B
  __shared__ float tot[WS];           // tot[k][q] = 1/sum_h
  const int b = blockIdx.x, kb = blockIdx.y;   // grid (8, 32)
  const int tid = threadIdx.x, wave = tid >> 6, lane = tid & 63;
  const int l31 = lane & 31, sg = lane >> 5;
  const int h = wave, bh = b * HN + h;
  const int k0 = kb * 32;
  const unsigned short* k1 = K1p + (size_t)bh * LQ * DPH;
  const unsigned short* k2 = K2p + (size_t)bh * LQ * DPH;
  const unsigned short* vt = V2T + (size_t)bh * DPH * LQ;
  float* mystrip = &strip[wave * WS];

  const int bk_ = tid & 31, bq2 = (tid >> 5) * 2;   // stage-B cell map

  bf16x8 bk[4];  // K1 rows k (score B operand), fixed for whole kernel
#pragma unroll
  for (int i = 0; i < 4; ++i)
    bk[i] = *(const bf16x8*)(k1 + (size_t)(k0 + l31) * DPH + i * 16 + sg * 8);

  // prologue: K2 fragments for q-step 0
  bf16x8 aq[4];
#pragma unroll
  for (int i = 0; i < 4; ++i)
    aq[i] = *(const bf16x8*)(k2 + (size_t)(l31) * DPH + i * 16 + sg * 8);

  f32x16 acc0 = zero16(), acc1 = zero16();

  for (int t = 0; t < LQ / 32; ++t) {
    const int q0 = t * 32;
    // ---- stage A: scores for THIS head (prefetched frags), exp, strip write
    f32x16 cs = zero16();
#pragma unroll
    for (int i = 0; i < 4; ++i) cs = mfma32(aq[i], bk[i], cs);  // C[row=q][col=k]
    // prefetch next step's K2 fragments (in flight across both barriers)
    const int qn = ((t + 1) & 31) * 32;
#pragma unroll
    for (int i = 0; i < 4; ++i)
      aq[i] = *(const bf16x8*)(k2 + (size_t)(qn + l31) * DPH + i * 16 + sg * 8);
    float pex[16];
#pragma unroll
    for (int r = 0; r < 16; ++r) pex[r] = __expf(cs[r]);
#pragma unroll
    for (int g = 0; g < 4; ++g) {           // q-group g covers q = g*8+4sg ..+3
      int qb = g * 8 + 4 * sg;
      *(f32x2*)&mystrip[l31 * SP + qb]     = (f32x2){pex[4 * g],     pex[4 * g + 1]};
      *(f32x2*)&mystrip[l31 * SP + qb + 2] = (f32x2){pex[4 * g + 2], pex[4 * g + 3]};
    }
    // V loads issued here; consumed after barrier B (vmcnt NOT drained at bar)
    bf16x8 v00 = *(const bf16x8*)(vt + (size_t)l31 * LQ + q0 + sg * 8);
    bf16x8 v01 = *(const bf16x8*)(vt + (size_t)l31 * LQ + q0 + 16 + sg * 8);
    bf16x8 v10 = *(const bf16x8*)(vt + (size_t)(32 + l31) * LQ + q0 + sg * 8);
    bf16x8 v11 = *(const bf16x8*)(vt + (size_t)(32 + l31) * LQ + q0 + 16 + sg * 8);
    lds_barrier();  // A: strips visible
    // ---- stage B: 512 threads sum one q-pair over 16 strips (b64 reads)
    if (tid < 512) {
      int off = bk_ * SP + bq2;
      f32x2 s = *(const f32x2*)&strip[off];
#pragma unroll
      for (int w = 1; w < 16; ++w) {
        f32x2 v = *(const f32x2*)&strip[w * WS + off];
        s.x += v.x; s.y += v.y;
      }
      f32x2 rc; rc.x = rcpf(s.x); rc.y = rcpf(s.y);
      *(f32x2*)&tot[off] = rc;
    }
    lds_barrier();  // B: tot visible
    // ---- stage C: b64 tot reads, normalize in-reg, pfrag, PV MFMA
    float p8a[8], p8b[8];
#pragma unroll
    for (int g = 0; g < 4; ++g) {
      int qb = g * 8 + 4 * sg;
      f32x2 t0 = *(const f32x2*)&tot[l31 * SP + qb];
      f32x2 t1 = *(const f32x2*)&tot[l31 * SP + qb + 2];
      float* dstp = (g < 2) ? &p8a[(g & 1) * 4] : &p8b[(g & 1) * 4];
      dstp[0] = pex[4 * g]     * t0.x;
      dstp[1] = pex[4 * g + 1] * t0.y;
      dstp[2] = pex[4 * g + 2] * t1.x;
      dstp[3] = pex[4 * g + 3] * t1.y;
    }
    bf16x8 pa0 = pfrag(p8a), pa1 = pfrag(p8b);
    acc0 = mfma32(pa0, v00, acc0);
    acc0 = mfma32(pa1, v01, acc0);
    acc1 = mfma32(pa0, v10, acc1);
    acc1 = mfma32(pa1, v11, acc1);
  }
#pragma unroll
  for (int r = 0; r < 16; ++r) {
    int k = k0 + (r & 3) + 8 * (r >> 2) + 4 * sg;
    size_t base = ((size_t)k * BN + b) * MN + h * 64;
    c21[base + l31] = f2bf(acc0[r]);
    c21[base + 32 + l31] = f2bf(acc1[r]);
  }
}

// ================================================================ host
extern "C" void kernel_launch(void* const* d_in, const int* in_sizes, int n_in,
                              void* d_out, int out_size, void* d_ws, size_t ws_size,
                              hipStream_t stream) {
  const float* ctx1 = (const float*)d_in[0];
  const float* ctx2 = (const float*)d_in[1];
  const float* Wk1 = (const float*)d_in[2];  const float* bk1 = (const float*)d_in[3];
  const float* Wv1 = (const float*)d_in[4];  const float* bv1 = (const float*)d_in[5];
  const float* Wk2 = (const float*)d_in[6];  const float* bk2 = (const float*)d_in[7];
  const float* Wv2 = (const float*)d_in[8];  const float* bv2 = (const float*)d_in[9];
  const float* Wf12 = (const float*)d_in[10]; const float* bf12 = (const float*)d_in[11];
  const float* Wf21 = (const float*)d_in[12]; const float* bf21 = (const float*)d_in[13];

  char* ws = (char*)d_ws;
  size_t off = 0;
  auto alloc = [&](size_t bytes) {
    void* p = ws + off;
    off += (bytes + 255) & ~(size_t)255;
    return p;
  };
  const size_t KV_BYTES = (size_t)BN * HN * LQ * DPH * 2;  // 16.78 MB

  unsigned short* wk1b = (unsigned short*)alloc((size_t)MN * D1N * 2);
  unsigned short* wv1b = (unsigned short*)alloc((size_t)MN * D1N * 2);
  unsigned short* wk2b = (unsigned short*)alloc((size_t)MN * D2N * 2);
  unsigned short* wv2b = (unsigned short*)alloc((size_t)MN * D2N * 2);
  unsigned short* wf12b = (unsigned short*)alloc((size_t)MN * MN * 2);
  unsigned short* wf21b = (unsigned short*)alloc((size_t)MN * MN * 2);
  unsigned short* K1buf = (unsigned short*)alloc(KV_BYTES);
  unsigned short* K2buf = (unsigned short*)alloc(KV_BYTES);
  unsigned short* V1T = (unsigned short*)alloc(KV_BYTES);   // scaled by 1/colsum
  unsigned short* V2T = (unsigned short*)alloc(KV_BYTES);
  float* invcs = (float*)alloc((size_t)BN * HN * LQ * 4);
  unsigned short* c12 = (unsigned short*)alloc(KV_BYTES);
  unsigned short* c21 = (unsigned short*)alloc(KV_BYTES);
  unsigned short* V1tmp = c12;  // alias: dead before c12 written
  unsigned short* V2tmp = c21;

  // ---- phase 1: ALL weight f32 -> bf16 conversions in one dispatch
  {
    CvtArgs a;
    a.src[0] = Wk1;  a.dst[0] = wk1b;
    a.src[1] = Wv1;  a.dst[1] = wv1b;
    a.src[2] = Wk2;  a.dst[2] = wk2b;
    a.src[3] = Wv2;  a.dst[3] = wv2b;
    a.src[4] = Wf12; a.dst[4] = wf12b;
    a.src[5] = Wf21; a.dst[5] = wf21b;
    const int n1 = MN * D1N / 8, n2 = MN * D2N / 8, n3 = MN * MN / 8;
    a.cum[0] = 0;
    a.cum[1] = n1;
    a.cum[2] = 2 * n1;
    a.cum[3] = 2 * n1 + n2;
    a.cum[4] = 2 * n1 + 2 * n2;
    a.cum[5] = 2 * n1 + 2 * n2 + n3;
    a.cum[6] = 2 * n1 + 2 * n2 + 2 * n3;
    cvt6_kernel<<<(a.cum[6] + 255) / 256, 256, 0, stream>>>(a);
  }

  // ---- phase 2: projections, K/V paired per context (sel in y-MSB), f32 A
  gemm_pair_f32_kernel<D1N><<<dim3(64, 16), 256, 0, stream>>>(
      ctx1, wk1b, wv1b, bk1, bv1, K1buf, V1tmp);
  gemm_pair_f32_kernel<D2N><<<dim3(64, 16), 256, 0, stream>>>(
      ctx2, wk2b, wv2b, bk2, bv2, K2buf, V2tmp);

  // ---- phase 3: colsum reduction (bh-major grid), then both V transposes
  col_reduce_kernel<<<dim3(BN * HN, LQ / 128), 256, 0, stream>>>(K1buf, K2buf, invcs);
  transpose2_kernel<<<dim3(LQ / 64, BN * HN, 2), 256, 0, stream>>>(
      V1tmp, V1T, invcs, V2tmp, V2T);

  // ---- phase 4: context passes (separate kernels; bh-major ctx12 grid)
  ctx12_kernel<<<dim3(BN * HN, LQ / 128), 256, 0, stream>>>(K1buf, K2buf, V1T, c12);
  ctx21_fused_kernel<<<dim3(BN, LQ / 32), 1024, 0, stream>>>(K1buf, K2buf, V2T, c21);

  // ---- phase 5: both final projections, gload_lds-staged, ONE dispatch
  float* out0 = (float*)d_out;                 // [L1, B, M] (context_2_to_1)
  float* out1 = out0 + (size_t)LQ * BN * MN;   // [L2, B, M] (context_1_to_2)
  gemm_lds_dual_kernel<MN><<<dim3(64, 16), 256, 0, stream>>>(
      c21, c12, wf21b, wf12b, bf21, bf12, out0, out1);
}

// Round 20
// 465.725 us; speedup vs baseline: 1.0118x; 1.0118x over previous
//
#include <hip/hip_runtime.h>
#include <hip/hip_bf16.h>

// Problem constants
constexpr int LQ  = 1024;  // L1 == L2 == 1024
constexpr int BN  = 8;
constexpr int D1N = 512;
constexpr int D2N = 1024;
constexpr int HN  = 16;
constexpr int MN  = 1024;
constexpr int DPH = 64;

typedef __attribute__((ext_vector_type(8)))  short bf16x8;   // 8 bf16 in 4 VGPRs
typedef __attribute__((ext_vector_type(2)))  float f32x2;
typedef __attribute__((ext_vector_type(4)))  float f32x4;
typedef __attribute__((ext_vector_type(16))) float f32x16;

__device__ __forceinline__ unsigned short f2bf(float f) {
  unsigned u = __float_as_uint(f);
  u += 0x7FFFu + ((u >> 16) & 1u);   // RNE
  return (unsigned short)(u >> 16);
}
__device__ __forceinline__ float bf2f(unsigned short u) {
  return __uint_as_float(((unsigned)u) << 16);
}
__device__ __forceinline__ float rcpf(float x) {
  float r;
  asm("v_rcp_f32 %0, %1" : "=v"(r) : "v"(x));
  return r;
}

__device__ __forceinline__ f32x4 mfma16(bf16x8 a, bf16x8 b, f32x4 c) {
  return __builtin_amdgcn_mfma_f32_16x16x32_bf16(a, b, c, 0, 0, 0);
}
__device__ __forceinline__ f32x16 mfma32(bf16x8 a, bf16x8 b, f32x16 c) {
  return __builtin_amdgcn_mfma_f32_32x32x16_bf16(a, b, c, 0, 0, 0);
}
__device__ __forceinline__ f32x16 zero16() {
  f32x16 z;
#pragma unroll
  for (int i = 0; i < 16; ++i) z[i] = 0.f;
  return z;
}

__device__ __forceinline__ unsigned cvtpk(float lo, float hi) {
  unsigned r;
  asm("v_cvt_pk_bf16_f32 %0, %1, %2" : "=v"(r) : "v"(lo), "v"(hi));
  return r;
}

// LDS-visibility barrier WITHOUT the vmcnt(0) drain __syncthreads() emits.
// (Correctness-proven R7-R19.)
__device__ __forceinline__ void lds_barrier() {
  asm volatile("s_waitcnt lgkmcnt(0)" ::: "memory");
  __builtin_amdgcn_s_barrier();
}

// Build PV A-fragment from 8 P values (C-layout row=(reg&3)+8*(reg>>2)+4*(lane>>5)).
__device__ __forceinline__ bf16x8 pfrag(const float* p) {
  unsigned x0 = cvtpk(p[0], p[1]), y0 = cvtpk(p[4], p[5]);
  unsigned x1 = cvtpk(p[2], p[3]), y1 = cvtpk(p[6], p[7]);
  asm volatile("v_permlane32_swap_b32 %0, %1" : "+v"(x0), "+v"(y0));
  asm volatile("v_permlane32_swap_b32 %0, %1" : "+v"(x1), "+v"(y1));
  union { unsigned u[4]; bf16x8 v; } r;
  r.u[0] = x0; r.u[1] = x1; r.u[2] = y0; r.u[3] = y1;
  return r.v;
}

__device__ __forceinline__ bf16x8 pack8(f32x4 p0, f32x4 p1) {
  bf16x8 o;
  o[0] = (short)f2bf(p0[0]); o[1] = (short)f2bf(p0[1]);
  o[2] = (short)f2bf(p0[2]); o[3] = (short)f2bf(p0[3]);
  o[4] = (short)f2bf(p1[0]); o[5] = (short)f2bf(p1[1]);
  o[6] = (short)f2bf(p1[2]); o[7] = (short)f2bf(p1[3]);
  return o;
}
// Fast frag-convert via v_cvt_pk_bf16_f32 (RNE)
__device__ __forceinline__ bf16x8 pack8q(f32x4 lo, f32x4 hi) {
  union { unsigned u[4]; bf16x8 v; } r;
  r.u[0] = cvtpk(lo[0], lo[1]); r.u[1] = cvtpk(lo[2], lo[3]);
  r.u[2] = cvtpk(hi[0], hi[1]); r.u[3] = cvtpk(hi[2], hi[3]);
  return r.v;
}

// ---------------------------------------------------------------- merged cvt
// All six weight f32->bf16 conversions in ONE dispatch (R18).
struct CvtArgs {
  const float* src[6];
  unsigned short* dst[6];
  int cum[7];   // cumulative x8-element counts
};
__global__ __launch_bounds__(256) void cvt6_kernel(CvtArgs a) {
  int i = blockIdx.x * blockDim.x + threadIdx.x;
  if (i >= a.cum[6]) return;
  int s = 0;
#pragma unroll
  for (int j = 1; j < 6; ++j) s += (i >= a.cum[j]) ? 1 : 0;
  int off = i - a.cum[s];
  const f32x4* sp = (const f32x4*)a.src[s];
  f32x4 x = sp[2 * off], y = sp[2 * off + 1];
  ((bf16x8*)a.dst[s])[off] = pack8(x, y);
}

// ---------------------------------------------------------------- staged GEMM
// A [rows,K] row-major (f32 if AF32, else bf16); W [1024,K] bf16 row-major.
// C = A @ W^T + bias. 128x128 tile, BK=32, reg-staged LDS, 2-phase with
// lgkmcnt-only barriers (R8-validated). AF32: cvt folded into LDS write.
// MODE 0: bf16 to [B,H,L,64]; MODE 2: f32 row-major [rows,1024]
template <int K, int MODE, bool AF32>
__device__ __forceinline__ void gemm_body(const void* __restrict__ Ap,
                                          const unsigned short* __restrict__ W,
                                          const float* __restrict__ bias,
                                          void* __restrict__ outp,
                                          int rowb, int colb) {
  __shared__ unsigned short As[128 * 40], Bs[128 * 40];
  const int tid = threadIdx.x, wave = tid >> 6, lane = tid & 63;
  const int lg = lane >> 4, lm = lane & 15;
  const int wrow = (wave >> 1) * 64, wcol = (wave & 1) * 64;
  const int sr = tid >> 1, sh = (tid & 1) * 16;
  const unsigned short* Arow = AF32 ? nullptr
      : (const unsigned short*)Ap + (size_t)(rowb + sr) * K + sh;
  const float* ArowF = AF32 ? (const float*)Ap + (size_t)(rowb + sr) * K + sh
                            : nullptr;
  const unsigned short* Wrow = W + (size_t)(colb + sr) * K + sh;

  f32x4 acc[4][4];
#pragma unroll
  for (int i = 0; i < 4; ++i)
#pragma unroll
    for (int j = 0; j < 4; ++j) acc[i][j] = (f32x4){0.f, 0.f, 0.f, 0.f};

  f32x4 fa0, fa1, fa2, fa3;
  bf16x8 a0, a1, b0, b1;
  if (AF32) {
    fa0 = *(const f32x4*)(ArowF);     fa1 = *(const f32x4*)(ArowF + 4);
    fa2 = *(const f32x4*)(ArowF + 8); fa3 = *(const f32x4*)(ArowF + 12);
  } else {
    a0 = *(const bf16x8*)(Arow);
    a1 = *(const bf16x8*)(Arow + 8);
  }
  b0 = *(const bf16x8*)(Wrow);
  b1 = *(const bf16x8*)(Wrow + 8);

  for (int kk = 0; kk < K; kk += 32) {
    lds_barrier();   // previous iteration's LDS frag reads complete
    if (AF32) {
      *(bf16x8*)&As[sr * 40 + sh]     = pack8q(fa0, fa1);
      *(bf16x8*)&As[sr * 40 + sh + 8] = pack8q(fa2, fa3);
    } else {
      *(bf16x8*)&As[sr * 40 + sh] = a0;
      *(bf16x8*)&As[sr * 40 + sh + 8] = a1;
    }
    *(bf16x8*)&Bs[sr * 40 + sh] = b0;
    *(bf16x8*)&Bs[sr * 40 + sh + 8] = b1;
    const int kn = (kk + 32 < K) ? kk + 32 : 0;   // clamped harmless reload
    if (AF32) {
      fa0 = *(const f32x4*)(ArowF + kn);     fa1 = *(const f32x4*)(ArowF + kn + 4);
      fa2 = *(const f32x4*)(ArowF + kn + 8); fa3 = *(const f32x4*)(ArowF + kn + 12);
    } else {
      a0 = *(const bf16x8*)(Arow + kn);
      a1 = *(const bf16x8*)(Arow + kn + 8);
    }
    b0 = *(const bf16x8*)(Wrow + kn);
    b1 = *(const bf16x8*)(Wrow + kn + 8);
    lds_barrier();   // staged writes visible
    bf16x8 af[4], wf[4];
#pragma unroll
    for (int i = 0; i < 4; ++i) af[i] = *(const bf16x8*)&As[(wrow + i * 16 + lm) * 40 + lg * 8];
#pragma unroll
    for (int j = 0; j < 4; ++j) wf[j] = *(const bf16x8*)&Bs[(wcol + j * 16 + lm) * 40 + lg * 8];
#pragma unroll
    for (int i = 0; i < 4; ++i)
#pragma unroll
      for (int j = 0; j < 4; ++j) acc[i][j] = mfma16(af[i], wf[j], acc[i][j]);
  }

#pragma unroll
  for (int j = 0; j < 4; ++j) {
    int col = colb + wcol + j * 16 + lm;
    float bs = bias[col];
#pragma unroll
    for (int i = 0; i < 4; ++i) {
#pragma unroll
      for (int r = 0; r < 4; ++r) {
        int row = rowb + wrow + i * 16 + lg * 4 + r;
        float v = acc[i][j][r] + bs;
        if (MODE == 0) {
          int l = row >> 3, bb = row & 7, h = col >> 6, d = col & 63;
          ((unsigned short*)outp)[(((size_t)(bb * HN + h)) * LQ + l) * DPH + d] = f2bf(v);
        } else {
          ((float*)outp)[(size_t)row * MN + col] = v;
        }
      }
    }
  }
}

// Paired projections (f32 A, cvt folded). sel in blockIdx.y-MSB so the K/V
// pair sharing an A-panel has the SAME blockIdx.x -> same XCD (R14).
template <int K>
__global__ __launch_bounds__(256) void gemm_pair_f32_kernel(
    const float* __restrict__ A,
    const unsigned short* __restrict__ W0, const unsigned short* __restrict__ W1,
    const float* __restrict__ b0, const float* __restrict__ b1,
    void* __restrict__ o0, void* __restrict__ o1) {
  const int sel = blockIdx.y >> 3;
  gemm_body<K, 0, true>(A, sel ? W1 : W0, sel ? b1 : b0, sel ? o1 : o0,
                        blockIdx.x * 128, (blockIdx.y & 7) * 128);
}

// Dual final projections in one dispatch: blockIdx.y>=8 -> second problem.
// (R19 lesson: gload_lds staging was neutral here; reg-staged body is the
// measured best at this shape.)
template <int K>
__global__ __launch_bounds__(256) void gemm_dual_kernel(
    const unsigned short* __restrict__ A0, const unsigned short* __restrict__ A1,
    const unsigned short* __restrict__ W0, const unsigned short* __restrict__ W1,
    const float* __restrict__ b0, const float* __restrict__ b1,
    void* __restrict__ o0, void* __restrict__ o1) {
  const int sel = blockIdx.y >> 3;
  gemm_body<K, 2, false>(sel ? A1 : A0, sel ? W1 : W0, sel ? b1 : b0,
                         sel ? o1 : o0, blockIdx.x * 128, (blockIdx.y & 7) * 128);
}

// ---------------------------------------------------------------- V transpose
// BOTH V transposes in one dispatch (grid.z: 0 = V1 scaled, 1 = V2 plain).
__global__ __launch_bounds__(256) void transpose2_kernel(
    const unsigned short* __restrict__ V1, unsigned short* __restrict__ VT1,
    const float* __restrict__ scale1,
    const unsigned short* __restrict__ V2, unsigned short* __restrict__ VT2) {
  __shared__ unsigned short t[64][72];
  const int which = blockIdx.z;
  const unsigned short* V = which ? V2 : V1;
  unsigned short* VT = which ? VT2 : VT1;
  const float* scale = which ? nullptr : scale1;
  int bh = blockIdx.y, l0 = blockIdx.x * 64;
  int tid = threadIdx.x;
  int r = tid >> 2, c0 = (tid & 3) * 16;
  const unsigned short* src = V + ((size_t)bh * LQ + l0 + r) * DPH + c0;
  bf16x8 v0 = *(const bf16x8*)(src);
  bf16x8 v1 = *(const bf16x8*)(src + 8);
  if (scale) {
    float sc = scale[(size_t)bh * LQ + l0 + r];
#pragma unroll
    for (int j = 0; j < 8; ++j) {
      v0[j] = (short)f2bf(bf2f((unsigned short)v0[j]) * sc);
      v1[j] = (short)f2bf(bf2f((unsigned short)v1[j]) * sc);
    }
  }
  *(bf16x8*)&t[r][c0] = v0;
  *(bf16x8*)&t[r][c0 + 8] = v1;
  __syncthreads();
  int d = tid >> 2, lc = (tid & 3) * 16;
  bf16x8 o0, o1;
#pragma unroll
  for (int j = 0; j < 8; ++j) {
    o0[j] = (short)t[lc + j][d];
    o1[j] = (short)t[lc + 8 + j][d];
  }
  unsigned short* dst = VT + ((size_t)bh * DPH + d) * LQ + l0 + lc;
  *(bf16x8*)dst = o0;
  *(bf16x8*)(dst + 8) = o1;
}

// ---------------------------------------------------------------- col reduce
// inv_colsum[bh,k] = 1/sum_q exp(s[q,k]).  bh-major grid; reg prefetch (R18).
__global__ __launch_bounds__(256) void col_reduce_kernel(const unsigned short* __restrict__ K1p,
                                                         const unsigned short* __restrict__ K2p,
                                                         float* __restrict__ inv_colsum) {
  int bh = blockIdx.x, kb = blockIdx.y * 128;
  int wave = threadIdx.x >> 6, lane = threadIdx.x & 63, l31 = lane & 31, sg = lane >> 5;
  int k0w = kb + wave * 32;
  const unsigned short* k1 = K1p + (size_t)bh * LQ * DPH;
  const unsigned short* k2 = K2p + (size_t)bh * LQ * DPH;
  bf16x8 bk[4];
#pragma unroll
  for (int i = 0; i < 4; ++i)
    bk[i] = *(const bf16x8*)(k1 + (size_t)(k0w + l31) * DPH + i * 16 + sg * 8);
  bf16x8 aq[4];
#pragma unroll
  for (int i = 0; i < 4; ++i)
    aq[i] = *(const bf16x8*)(k2 + (size_t)(l31) * DPH + i * 16 + sg * 8);
  float tot = 0.f;
  for (int q0 = 0; q0 < LQ; q0 += 32) {
    const int qn = (q0 + 32) & (LQ - 1);   // harmless wrap reload on last
    bf16x8 aqn[4];
#pragma unroll
    for (int i = 0; i < 4; ++i)
      aqn[i] = *(const bf16x8*)(k2 + (size_t)(qn + l31) * DPH + i * 16 + sg * 8);
    f32x16 cs = zero16();
#pragma unroll
    for (int i = 0; i < 4; ++i) cs = mfma32(aq[i], bk[i], cs);
#pragma unroll
    for (int r = 0; r < 16; ++r) tot += __expf(cs[r]);
#pragma unroll
    for (int i = 0; i < 4; ++i) aq[i] = aqn[i];
  }
  tot += __shfl_xor(tot, 32);
  if (lane < 32) inv_colsum[(size_t)bh * LQ + k0w + lane] = 1.0f / tot;
}

// ---------------------------------------------------------------- ctx 1->2
// out[q][d] = sum_k exp(s[q,k]) * V1s[k][d]   (V1s pre-scaled by 1/colsum)
// bh-major grid; reg prefetch of next k-tile K1 frags (R18).
__global__ __launch_bounds__(256) void ctx12_kernel(const unsigned short* __restrict__ K1p,
                                                    const unsigned short* __restrict__ K2p,
                                                    const unsigned short* __restrict__ V1Ts,
                                                    unsigned short* __restrict__ c12) {
  int bh = blockIdx.x, b = bh >> 4, h = bh & 15;
  int wave = threadIdx.x >> 6, lane = threadIdx.x & 63, l31 = lane & 31, sg = lane >> 5;
  int q0 = blockIdx.y * 128 + wave * 32;
  const unsigned short* k1 = K1p + (size_t)bh * LQ * DPH;
  const unsigned short* k2 = K2p + (size_t)bh * LQ * DPH;
  const unsigned short* vt = V1Ts + (size_t)bh * DPH * LQ;

  bf16x8 bq[4];  // K2 rows q (B operand of score), hoisted
#pragma unroll
  for (int i = 0; i < 4; ++i)
    bq[i] = *(const bf16x8*)(k2 + (size_t)(q0 + l31) * DPH + i * 16 + sg * 8);

  bf16x8 ak[4];
#pragma unroll
  for (int i = 0; i < 4; ++i)
    ak[i] = *(const bf16x8*)(k1 + (size_t)(l31) * DPH + i * 16 + sg * 8);

  f32x16 acc0 = zero16(), acc1 = zero16();
  for (int k0 = 0; k0 < LQ; k0 += 32) {
    const int kn = (k0 + 32) & (LQ - 1);   // harmless wrap reload on last
    bf16x8 akn[4];
#pragma unroll
    for (int i = 0; i < 4; ++i)
      akn[i] = *(const bf16x8*)(k1 + (size_t)(kn + l31) * DPH + i * 16 + sg * 8);
    f32x16 cs = zero16();
#pragma unroll
    for (int i = 0; i < 4; ++i) cs = mfma32(ak[i], bq[i], cs);  // C[k][q]
    float p[16];
#pragma unroll
    for (int r = 0; r < 16; ++r) p[r] = __expf(cs[r]);
    bf16x8 pa0 = pfrag(p), pa1 = pfrag(p + 8);
    bf16x8 v00 = *(const bf16x8*)(vt + (size_t)l31 * LQ + k0 + sg * 8);
    bf16x8 v01 = *(const bf16x8*)(vt + (size_t)l31 * LQ + k0 + 16 + sg * 8);
    bf16x8 v10 = *(const bf16x8*)(vt + (size_t)(32 + l31) * LQ + k0 + sg * 8);
    bf16x8 v11 = *(const bf16x8*)(vt + (size_t)(32 + l31) * LQ + k0 + 16 + sg * 8);
    acc0 = mfma32(pa0, v00, acc0);
    acc0 = mfma32(pa1, v01, acc0);
    acc1 = mfma32(pa0, v10, acc1);
    acc1 = mfma32(pa1, v11, acc1);
#pragma unroll
    for (int i = 0; i < 4; ++i) ak[i] = akn[i];
  }
#pragma unroll
  for (int r = 0; r < 16; ++r) {
    int q = q0 + (r & 3) + 8 * (r >> 2) + 4 * sg;
    size_t base = ((size_t)q * BN + b) * MN + h * 64;
    c12[base + l31] = f2bf(acc0[r]);
    c12[base + 32 + l31] = f2bf(acc1[r]);
  }
}

// ---------------------------------------------------------------- ctx 2->1 FUSED
// v4 (R8/R14, best measured 131us): raw lds_barrier (no vmcnt drain -> V
// loads span 2 barriers, K2 loads prefetched one step ahead). Verified.
__global__ __launch_bounds__(1024) void ctx21_fused_kernel(const unsigned short* __restrict__ K1p,
                                                           const unsigned short* __restrict__ K2p,
                                                           const unsigned short* __restrict__ V2T,
                                                           unsigned short* __restrict__ c21) {
  constexpr int SP = 34;              // floats per k-row (pad)
  constexpr int WS = 32 * SP;         // 1088 floats per wave strip
  __shared__ float strip[16 * WS];    // 69632 B
  __shared__ float tot[WS];           // tot[k][q] = 1/sum_h
  const int b = blockIdx.x, kb = blockIdx.y;   // grid (8, 32)
  const int tid = threadIdx.x, wave = tid >> 6, lane = tid & 63;
  const int l31 = lane & 31, sg = lane >> 5;
  const int h = wave, bh = b * HN + h;
  const int k0 = kb * 32;
  const unsigned short* k1 = K1p + (size_t)bh * LQ * DPH;
  const unsigned short* k2 = K2p + (size_t)bh * LQ * DPH;
  const unsigned short* vt = V2T + (size_t)bh * DPH * LQ;
  float* mystrip = &strip[wave * WS];

  const int bk_ = tid & 31, bq2 = (tid >> 5) * 2;   // stage-B cell map

  bf16x8 bk[4];  // K1 rows k (score B operand), fixed for whole kernel
#pragma unroll
  for (int i = 0; i < 4; ++i)
    bk[i] = *(const bf16x8*)(k1 + (size_t)(k0 + l31) * DPH + i * 16 + sg * 8);

  // prologue: K2 fragments for q-step 0
  bf16x8 aq[4];
#pragma unroll
  for (int i = 0; i < 4; ++i)
    aq[i] = *(const bf16x8*)(k2 + (size_t)(l31) * DPH + i * 16 + sg * 8);

  f32x16 acc0 = zero16(), acc1 = zero16();

  for (int t = 0; t < LQ / 32; ++t) {
    const int q0 = t * 32;
    // ---- stage A: scores for THIS head (prefetched frags), exp, strip write
    f32x16 cs = zero16();
#pragma unroll
    for (int i = 0; i < 4; ++i) cs = mfma32(aq[i], bk[i], cs);  // C[row=q][col=k]
    // prefetch next step's K2 fragments (in flight across both barriers)
    const int qn = ((t + 1) & 31) * 32;
#pragma unroll
    for (int i = 0; i < 4; ++i)
      aq[i] = *(const bf16x8*)(k2 + (size_t)(qn + l31) * DPH + i * 16 + sg * 8);
    float pex[16];
#pragma unroll
    for (int r = 0; r < 16; ++r) pex[r] = __expf(cs[r]);
#pragma unroll
    for (int g = 0; g < 4; ++g) {           // q-group g covers q = g*8+4sg ..+3
      int qb = g * 8 + 4 * sg;
      *(f32x2*)&mystrip[l31 * SP + qb]     = (f32x2){pex[4 * g],     pex[4 * g + 1]};
      *(f32x2*)&mystrip[l31 * SP + qb + 2] = (f32x2){pex[4 * g + 2], pex[4 * g + 3]};
    }
    // V loads issued here; consumed after barrier B (vmcnt NOT drained at bar)
    bf16x8 v00 = *(const bf16x8*)(vt + (size_t)l31 * LQ + q0 + sg * 8);
    bf16x8 v01 = *(const bf16x8*)(vt + (size_t)l31 * LQ + q0 + 16 + sg * 8);
    bf16x8 v10 = *(const bf16x8*)(vt + (size_t)(32 + l31) * LQ + q0 + sg * 8);
    bf16x8 v11 = *(const bf16x8*)(vt + (size_t)(32 + l31) * LQ + q0 + 16 + sg * 8);
    lds_barrier();  // A: strips visible
    // ---- stage B: 512 threads sum one q-pair over 16 strips (b64 reads)
    if (tid < 512) {
      int off = bk_ * SP + bq2;
      f32x2 s = *(const f32x2*)&strip[off];
#pragma unroll
      for (int w = 1; w < 16; ++w) {
        f32x2 v = *(const f32x2*)&strip[w * WS + off];
        s.x += v.x; s.y += v.y;
      }
      f32x2 rc; rc.x = rcpf(s.x); rc.y = rcpf(s.y);
      *(f32x2*)&tot[off] = rc;
    }
    lds_barrier();  // B: tot visible
    // ---- stage C: b64 tot reads, normalize in-reg, pfrag, PV MFMA
    float p8a[8], p8b[8];
#pragma unroll
    for (int g = 0; g < 4; ++g) {
      int qb = g * 8 + 4 * sg;
      f32x2 t0 = *(const f32x2*)&tot[l31 * SP + qb];
      f32x2 t1 = *(const f32x2*)&tot[l31 * SP + qb + 2];
      float* dstp = (g < 2) ? &p8a[(g & 1) * 4] : &p8b[(g & 1) * 4];
      dstp[0] = pex[4 * g]     * t0.x;
      dstp[1] = pex[4 * g + 1] * t0.y;
      dstp[2] = pex[4 * g + 2] * t1.x;
      dstp[3] = pex[4 * g + 3] * t1.y;
    }
    bf16x8 pa0 = pfrag(p8a), pa1 = pfrag(p8b);
    acc0 = mfma32(pa0, v00, acc0);
    acc0 = mfma32(pa1, v01, acc0);
    acc1 = mfma32(pa0, v10, acc1);
    acc1 = mfma32(pa1, v11, acc1);
  }
#pragma unroll
  for (int r = 0; r < 16; ++r) {
    int k = k0 + (r & 3) + 8 * (r >> 2) + 4 * sg;
    size_t base = ((size_t)k * BN + b) * MN + h * 64;
    c21[base + l31] = f2bf(acc0[r]);
    c21[base + 32 + l31] = f2bf(acc1[r]);
  }
}

// ================================================================ host
extern "C" void kernel_launch(void* const* d_in, const int* in_sizes, int n_in,
                              void* d_out, int out_size, void* d_ws, size_t ws_size,
                              hipStream_t stream) {
  const float* ctx1 = (const float*)d_in[0];
  const float* ctx2 = (const float*)d_in[1];
  const float* Wk1 = (const float*)d_in[2];  const float* bk1 = (const float*)d_in[3];
  const float* Wv1 = (const float*)d_in[4];  const float* bv1 = (const float*)d_in[5];
  const float* Wk2 = (const float*)d_in[6];  const float* bk2 = (const float*)d_in[7];
  const float* Wv2 = (const float*)d_in[8];  const float* bv2 = (const float*)d_in[9];
  const float* Wf12 = (const float*)d_in[10]; const float* bf12 = (const float*)d_in[11];
  const float* Wf21 = (const float*)d_in[12]; const float* bf21 = (const float*)d_in[13];

  char* ws = (char*)d_ws;
  size_t off = 0;
  auto alloc = [&](size_t bytes) {
    void* p = ws + off;
    off += (bytes + 255) & ~(size_t)255;
    return p;
  };
  const size_t KV_BYTES = (size_t)BN * HN * LQ * DPH * 2;  // 16.78 MB

  unsigned short* wk1b = (unsigned short*)alloc((size_t)MN * D1N * 2);
  unsigned short* wv1b = (unsigned short*)alloc((size_t)MN * D1N * 2);
  unsigned short* wk2b = (unsigned short*)alloc((size_t)MN * D2N * 2);
  unsigned short* wv2b = (unsigned short*)alloc((size_t)MN * D2N * 2);
  unsigned short* wf12b = (unsigned short*)alloc((size_t)MN * MN * 2);
  unsigned short* wf21b = (unsigned short*)alloc((size_t)MN * MN * 2);
  unsigned short* K1buf = (unsigned short*)alloc(KV_BYTES);
  unsigned short* K2buf = (unsigned short*)alloc(KV_BYTES);
  unsigned short* V1T = (unsigned short*)alloc(KV_BYTES);   // scaled by 1/colsum
  unsigned short* V2T = (unsigned short*)alloc(KV_BYTES);
  float* invcs = (float*)alloc((size_t)BN * HN * LQ * 4);
  unsigned short* c12 = (unsigned short*)alloc(KV_BYTES);
  unsigned short* c21 = (unsigned short*)alloc(KV_BYTES);
  unsigned short* V1tmp = c12;  // alias: dead before c12 written
  unsigned short* V2tmp = c21;

  // ---- phase 1: ALL weight f32 -> bf16 conversions in one dispatch
  {
    CvtArgs a;
    a.src[0] = Wk1;  a.dst[0] = wk1b;
    a.src[1] = Wv1;  a.dst[1] = wv1b;
    a.src[2] = Wk2;  a.dst[2] = wk2b;
    a.src[3] = Wv2;  a.dst[3] = wv2b;
    a.src[4] = Wf12; a.dst[4] = wf12b;
    a.src[5] = Wf21; a.dst[5] = wf21b;
    const int n1 = MN * D1N / 8, n2 = MN * D2N / 8, n3 = MN * MN / 8;
    a.cum[0] = 0;
    a.cum[1] = n1;
    a.cum[2] = 2 * n1;
    a.cum[3] = 2 * n1 + n2;
    a.cum[4] = 2 * n1 + 2 * n2;
    a.cum[5] = 2 * n1 + 2 * n2 + n3;
    a.cum[6] = 2 * n1 + 2 * n2 + 2 * n3;
    cvt6_kernel<<<(a.cum[6] + 255) / 256, 256, 0, stream>>>(a);
  }

  // ---- phase 2: projections, K/V paired per context (sel in y-MSB), f32 A
  gemm_pair_f32_kernel<D1N><<<dim3(64, 16), 256, 0, stream>>>(
      ctx1, wk1b, wv1b, bk1, bv1, K1buf, V1tmp);
  gemm_pair_f32_kernel<D2N><<<dim3(64, 16), 256, 0, stream>>>(
      ctx2, wk2b, wv2b, bk2, bv2, K2buf, V2tmp);

  // ---- phase 3: colsum reduction (bh-major grid), then both V transposes
  col_reduce_kernel<<<dim3(BN * HN, LQ / 128), 256, 0, stream>>>(K1buf, K2buf, invcs);
  transpose2_kernel<<<dim3(LQ / 64, BN * HN, 2), 256, 0, stream>>>(
      V1tmp, V1T, invcs, V2tmp, V2T);

  // ---- phase 4: context passes (separate kernels; bh-major ctx12 grid)
  ctx12_kernel<<<dim3(BN * HN, LQ / 128), 256, 0, stream>>>(K1buf, K2buf, V1T, c12);
  ctx21_fused_kernel<<<dim3(BN, LQ / 32), 1024, 0, stream>>>(K1buf, K2buf, V2T, c21);

  // ---- phase 5: both final projections in ONE dispatch -> f32 d_out
  float* out0 = (float*)d_out;                 // [L1, B, M] (context_2_to_1)
  float* out1 = out0 + (size_t)LQ * BN * MN;   // [L2, B, M] (context_1_to_2)
  gemm_dual_kernel<MN><<<dim3(64, 16), 256, 0, stream>>>(
      c21, c12, wf21b, wf12b, bf21, bf12, out0, out1);
}